// Round 6
// baseline (6883.501 us; speedup 1.0000x reference)
//
#include <hip/hip_runtime.h>

#define EDIM   128
#define NE     1024
#define ROWS   64        // rows per block (= lanes per wave)
#define THREADS 256      // 4 waves; wave w = code-group w
#define CPT    8         // codes per thread per pass
#define CPP    32        // codes per pass (4 waves x 8)
#define NPASS  (NE/CPP)  // 32

// Bit-exact reproduction of numpy fp32 (locked since round 2, absmax 0.0):
//   d = (sum(x*x,1,keepdims) + sum(W*W,1)) - 2*matmul(x, W.T)
//   idx = argmin(d,1) (first index on ties); z_q = W[idx]
//  - sums: numpy pairwise 8-accumulator stride-8 pattern, mul then add
//  - matmul: sequential-j fmaf chain per (row,k); code-tiling never splits j
//  - d: fl32(fl32(xx + wk2) - fl32(2*dot)), strict-< argmin, global
//    first-index preserved via (d==bd && k<bk) in the cross-wave reduce.
// Round-6: lane=row mapping. x transposed in LDS -> ds_read_b128 delivers
// 1024B/instr (v5 wasted 64x on uniform broadcast reads). W operand is
// wave-uniform (readfirstlane'd code-group) -> scalar-path loads, 8 float4
// in flight, immediate offsets. x read from HBM exactly once.

__global__ __launch_bounds__(256, 4) void vq_v6(
    const float* __restrict__ x, const float* __restrict__ W,
    float* __restrict__ zq, float* __restrict__ idxout)
{
#pragma clang fp contract(off)
    __shared__ float4 sxT[32 * ROWS];   // [j4][row] transposed x tile, 32 KB
    __shared__ float  swsq[NE];         // 4 KB
    __shared__ float  rd[4][ROWS];      // per-code-group best d
    __shared__ int    rk[4][ROWS];      // per-code-group best k
    __shared__ int    sbest[ROWS];

    const int tid  = threadIdx.x;
    const int lane = tid & 63;                                  // = my row
    const int cg   = __builtin_amdgcn_readfirstlane(tid >> 6);  // wave-uniform

    const long long row0 = (long long)blockIdx.x * ROWS;

    const float4* x4 = reinterpret_cast<const float4*>(x);
    const float4* W4 = reinterpret_cast<const float4*>(W);

    // ---- stage x tile transposed (global side coalesced; one-time LDS
    //      write conflicts are negligible) ----
    for (int i = tid; i < ROWS * 32; i += THREADS) {
        int r = i >> 5, j4 = i & 31;
        sxT[j4 * ROWS + r] = x4[row0 * 32 + i];
    }

    // ---- swsq[k] = np.sum(W*W,1): numpy pairwise 8-acc pattern ----
    for (int k = tid; k < NE; k += THREADS) {
        const float4* wr = W4 + (size_t)k * 32;
        float4 A = wr[0], B = wr[1];
        float r0 = A.x * A.x, r1 = A.y * A.y, r2 = A.z * A.z, r3 = A.w * A.w;
        float r4 = B.x * B.x, r5 = B.y * B.y, r6 = B.z * B.z, r7 = B.w * B.w;
        #pragma unroll
        for (int i = 2; i < 32; i += 2) {
            float4 C = wr[i], D = wr[i + 1];
            r0 += C.x * C.x; r1 += C.y * C.y; r2 += C.z * C.z; r3 += C.w * C.w;
            r4 += D.x * D.x; r5 += D.y * D.y; r6 += D.z * D.z; r7 += D.w * D.w;
        }
        swsq[k] = ((r0 + r1) + (r2 + r3)) + ((r4 + r5) + (r6 + r7));
    }
    __syncthreads();

    // ---- xx for my row (numpy pairwise 8-acc, from transposed LDS) ----
    float xxv;
    {
        float4 A = sxT[0 * ROWS + lane], B = sxT[1 * ROWS + lane];
        float r0 = A.x * A.x, r1 = A.y * A.y, r2 = A.z * A.z, r3 = A.w * A.w;
        float r4 = B.x * B.x, r5 = B.y * B.y, r6 = B.z * B.z, r7 = B.w * B.w;
        #pragma unroll
        for (int i = 2; i < 32; i += 2) {
            float4 C = sxT[i * ROWS + lane], D = sxT[(i + 1) * ROWS + lane];
            r0 += C.x * C.x; r1 += C.y * C.y; r2 += C.z * C.z; r3 += C.w * C.w;
            r4 += D.x * D.x; r5 += D.y * D.y; r6 += D.z * D.z; r7 += D.w * D.w;
        }
        xxv = ((r0 + r1) + (r2 + r3)) + ((r4 + r5) + (r6 + r7));
    }

    // ---- main: 32 passes x 8 codes; full j-chain inside each pass ----
    float dbest = 3.4e38f;
    int   bestk = 0;

    #pragma unroll 1
    for (int p = 0; p < NPASS; ++p) {
        const float4* Wp = W4 + (size_t)(p * CPP + cg * CPT) * 32;  // uniform

        float acc[CPT];
        #pragma unroll
        for (int c = 0; c < CPT; ++c) acc[c] = 0.f;

        #pragma unroll
        for (int j4 = 0; j4 < 32; ++j4) {
            float4 a = sxT[j4 * ROWS + lane];   // 64 lanes x 16B contiguous
            #pragma unroll
            for (int c = 0; c < CPT; ++c) {
                float4 w = Wp[c * 32 + j4];     // wave-uniform, imm offset
                acc[c] = fmaf(a.x, w.x, acc[c]);
                acc[c] = fmaf(a.y, w.y, acc[c]);
                acc[c] = fmaf(a.z, w.z, acc[c]);
                acc[c] = fmaf(a.w, w.w, acc[c]);
            }
        }

        #pragma unroll
        for (int c = 0; c < CPT; ++c) {
            int k = p * CPP + cg * CPT + c;      // ascending per thread
            float t1 = xxv + swsq[k];            // fl(xx + wk2)
            float d  = t1 - (acc[c] + acc[c]);   // fl(t1 - fl(2*dot))
            if (d < dbest) { dbest = d; bestk = k; }   // strict <
        }
    }

    rd[cg][lane] = dbest;
    rk[cg][lane] = bestk;
    __syncthreads();

    // ---- per-row reduce over the 4 code-groups (global first-index) ----
    if (tid < ROWS) {
        float bd = rd[0][tid]; int bk = rk[0][tid];
        #pragma unroll
        for (int g = 1; g < 4; ++g) {
            float d2 = rd[g][tid]; int k2 = rk[g][tid];
            if (d2 < bd || (d2 == bd && k2 < bk)) { bd = d2; bk = k2; }
        }
        sbest[tid] = bk;
        idxout[row0 + tid] = (float)bk;
    }
    __syncthreads();

    // ---- z_q gather (coalesced float4; bit-exact copy of W rows) ----
    float4* zq4 = reinterpret_cast<float4*>(zq);
    for (int i = tid; i < ROWS * 32; i += THREADS) {
        int r = i >> 5, c4 = i & 31;
        zq4[row0 * 32 + i] = W4[(size_t)sbest[r] * 32 + c4];
    }
}

extern "C" void kernel_launch(void* const* d_in, const int* in_sizes, int n_in,
                              void* d_out, int out_size, void* d_ws, size_t ws_size,
                              hipStream_t stream) {
    (void)n_in; (void)out_size; (void)d_ws; (void)ws_size;
    const float* x = (const float*)d_in[0];
    const float* W = (const float*)d_in[1];
    const int Nrows = in_sizes[0] / EDIM;           // 262144

    float* zqp    = (float*)d_out;
    float* idxout = zqp + (size_t)Nrows * EDIM;     // indices stored as float values

    vq_v6<<<dim3(Nrows / ROWS), dim3(THREADS), 0, stream>>>(x, W, zqp, idxout);
}

// Round 7
// 1294.950 us; speedup vs baseline: 5.3157x; 5.3157x over previous
//
#include <hip/hip_runtime.h>

#define EDIM 128
#define NE   1024
#define TAU  2e-4f     // approx top-2 gap below which numpy grid ties are possible

typedef __attribute__((address_space(3))) void       lds_t;
typedef const __attribute__((address_space(1))) void gm_t;
typedef short v8s __attribute__((ext_vector_type(8)));    // 8 bf16 (4 VGPR)
typedef float v4f __attribute__((ext_vector_type(4)));

__device__ inline unsigned bf16_rne(float f) {
    unsigned u = __float_as_uint(f);
    return (u + 0x7fffu + ((u >> 16) & 1u)) >> 16;
}
__device__ inline float bf16_tof(unsigned h) { return __uint_as_float(h << 16); }

// ---------------- kernel A: W -> bf16 hi/lo, numpy-exact swsq, zero counter ----
__global__ void vq_prep(const float* __restrict__ W,
                        unsigned short* __restrict__ whi,
                        unsigned short* __restrict__ wlo,
                        float* __restrict__ swsq_ws, int* __restrict__ rcnt)
{
#pragma clang fp contract(off)
    const int t = blockIdx.x * 256 + threadIdx.x;     // grid 128x256 = 32768
    if (t == 0) *rcnt = 0;
    for (int i = t; i < NE * EDIM; i += 32768) {
        float v = W[i];
        unsigned h = bf16_rne(v);
        whi[i] = (unsigned short)h;
        wlo[i] = (unsigned short)bf16_rne(v - bf16_tof(h));
    }
    if (t < NE) {   // numpy pairwise 8-acc pattern (validated rounds 2-6)
        const float4* wr = reinterpret_cast<const float4*>(W) + (size_t)t * 32;
        float4 A = wr[0], B = wr[1];
        float r0 = A.x*A.x, r1 = A.y*A.y, r2 = A.z*A.z, r3 = A.w*A.w;
        float r4 = B.x*B.x, r5 = B.y*B.y, r6 = B.z*B.z, r7 = B.w*B.w;
        #pragma unroll
        for (int i = 2; i < 32; i += 2) {
            float4 C = wr[i], D = wr[i + 1];
            r0 += C.x*C.x; r1 += C.y*C.y; r2 += C.z*C.z; r3 += C.w*C.w;
            r4 += D.x*D.x; r5 += D.y*D.y; r6 += D.z*D.z; r7 += D.w*D.w;
        }
        swsq_ws[t] = ((r0 + r1) + (r2 + r3)) + ((r4 + r5) + (r6 + r7));
    }
}

// ---------------- stage 1: MFMA approximate scores + top-2 + flag ----------------
// block = 256 thr = 4 waves; wave w owns rows [blk*64 + w*16 .. +15], all 1024 codes.
// A-frag (16x32 bf16): lane l -> row l&15, k = (l>>4)*8 + e
// B-frag:              lane l -> code l&15, k = (l>>4)*8 + e
// C    :               lane l, reg r -> row (l>>4)*4 + r, code l&15
__global__ __launch_bounds__(256, 4) void vq_mfma(
    const float* __restrict__ x,
    const unsigned short* __restrict__ whi, const unsigned short* __restrict__ wlo,
    const float* __restrict__ W, const float* __restrict__ swsq_ws,
    float* __restrict__ zq, float* __restrict__ idxout,
    int* __restrict__ rcnt, int* __restrict__ rlist)
{
    __shared__ unsigned short wt[2][2][16 * EDIM];   // [buf][hi/lo][code][k], 16 KB
    __shared__ float sswsq[NE];                      // 4 KB
    __shared__ int   sbest[64];

    const int tid = threadIdx.x;
    const int wid = tid >> 6;
    const int l   = tid & 63;
    const int m   = l & 15;          // A-row / B-code within tile
    const int g   = l >> 4;          // k-group
    const int kb  = g * 8;

    const long long row0 = (long long)blockIdx.x * 64;
    const float4* x4 = reinterpret_cast<const float4*>(x);
    const float4* W4 = reinterpret_cast<const float4*>(W);

    // stage swsq into LDS (256 x float4 = 4 KB)
    reinterpret_cast<float4*>(sswsq)[tid] = reinterpret_cast<const float4*>(swsq_ws)[tid];

    // stage W tile 0 (hi+lo, 4 KB each, one global_load_lds per 256-thread block)
    __builtin_amdgcn_global_load_lds((gm_t*)(whi + tid * 8), (lds_t*)&wt[0][0][tid * 8], 16, 0, 0);
    __builtin_amdgcn_global_load_lds((gm_t*)(wlo + tid * 8), (lds_t*)&wt[0][1][tid * 8], 16, 0, 0);

    // ---- load + split my A-fragments: row0+wid*16+m, k in {ks*32+kb .. +7} ----
    const long long rowA = row0 + wid * 16 + m;
    v8s a_hi[4], a_lo[4];
    #pragma unroll
    for (int ks = 0; ks < 4; ++ks) {
        float4 p0 = x4[rowA * 32 + ks * 8 + (kb >> 2)];
        float4 p1 = x4[rowA * 32 + ks * 8 + (kb >> 2) + 1];
        float v[8] = {p0.x, p0.y, p0.z, p0.w, p1.x, p1.y, p1.z, p1.w};
        #pragma unroll
        for (int e = 0; e < 8; ++e) {
            unsigned h = bf16_rne(v[e]);
            a_hi[ks][e] = (short)h;
            a_lo[ks][e] = (short)bf16_rne(v[e] - bf16_tof(h));
        }
    }
    __syncthreads();   // tile0 + swsq ready

    float best[4] = {3.4e38f, 3.4e38f, 3.4e38f, 3.4e38f};
    float sec[4]  = {3.4e38f, 3.4e38f, 3.4e38f, 3.4e38f};
    int   bk[4]   = {0, 0, 0, 0};

    #pragma unroll 1
    for (int t = 0; t < 64; ++t) {
        const int buf = t & 1;
        if (t + 1 < 64) {   // prefetch next 16-code tile
            __builtin_amdgcn_global_load_lds((gm_t*)(whi + (t + 1) * 2048 + tid * 8),
                                             (lds_t*)&wt[buf ^ 1][0][tid * 8], 16, 0, 0);
            __builtin_amdgcn_global_load_lds((gm_t*)(wlo + (t + 1) * 2048 + tid * 8),
                                             (lds_t*)&wt[buf ^ 1][1][tid * 8], 16, 0, 0);
        }

        v4f acc = {0.f, 0.f, 0.f, 0.f};
        #pragma unroll
        for (int ks = 0; ks < 4; ++ks) {
            v8s bh = *(const v8s*)&wt[buf][0][m * EDIM + ks * 32 + kb];
            v8s bl = *(const v8s*)&wt[buf][1][m * EDIM + ks * 32 + kb];
            acc = __builtin_amdgcn_mfma_f32_16x16x32_bf16(a_hi[ks], bh, acc, 0, 0, 0);
            acc = __builtin_amdgcn_mfma_f32_16x16x32_bf16(a_lo[ks], bh, acc, 0, 0, 0);
            acc = __builtin_amdgcn_mfma_f32_16x16x32_bf16(a_hi[ks], bl, acc, 0, 0, 0);
        }

        const int k = t * 16 + m;
        const float wk2 = sswsq[k];
        #pragma unroll
        for (int r = 0; r < 4; ++r) {
            float s = fmaf(-2.f, acc[r], wk2);   // s = wk2 - 2*dot (true-value proxy)
            bool lt = s < best[r];
            sec[r]  = lt ? best[r] : fminf(sec[r], s);
            bk[r]   = lt ? k : bk[r];
            best[r] = lt ? s : best[r];
        }
        __syncthreads();
    }

    // ---- cross-lane top-2 merge over the 16 code-lanes (masks 1,2,4,8) ----
    #pragma unroll
    for (int r = 0; r < 4; ++r) {
        #pragma unroll
        for (int mk = 1; mk < 16; mk <<= 1) {
            float ob = __shfl_xor(best[r], mk);
            int   ok = __shfl_xor(bk[r],   mk);
            float os = __shfl_xor(sec[r],  mk);
            bool take = (ob < best[r]) || (ob == best[r] && ok < bk[r]);
            float loser = take ? best[r] : ob;
            sec[r]  = fminf(fminf(sec[r], os), loser);
            best[r] = take ? ob : best[r];
            bk[r]   = take ? ok : bk[r];
        }
    }

    if (m == 0) {
        #pragma unroll
        for (int r = 0; r < 4; ++r) {
            int rowL = wid * 16 + g * 4 + r;
            sbest[rowL] = bk[r];
            idxout[row0 + rowL] = (float)bk[r];          // final unless flagged
            if (sec[r] - best[r] <= TAU) {               // grid tie possible
                int slot = atomicAdd(rcnt, 1);
                rlist[slot] = (int)(row0 + rowL);
            }
        }
    }
    __syncthreads();

    // ---- z_q gather (flagged rows re-written by rescue) ----
    float4* zq4 = reinterpret_cast<float4*>(zq);
    for (int i = tid; i < 64 * 32; i += 256) {
        int r = i >> 5, c4 = i & 31;
        zq4[row0 * 32 + i] = W4[(size_t)sbest[r] * 32 + c4];
    }
}

// ---------------- stage 2: numpy-bit-exact rescan of flagged rows ----------------
__global__ __launch_bounds__(64) void vq_rescue(
    const float* __restrict__ x, const float* __restrict__ W,
    const float* __restrict__ swsq_ws,
    float* __restrict__ zq, float* __restrict__ idxout,
    const int* __restrict__ rcnt, const int* __restrict__ rlist, int nmax)
{
#pragma clang fp contract(off)
    int n = *rcnt; if (n > nmax) n = nmax;
    const int lane = threadIdx.x;
    const float4* W4 = reinterpret_cast<const float4*>(W);

    for (int i = blockIdx.x; i < n; i += gridDim.x) {
        const int row = rlist[i];
        const float4* xr4 = reinterpret_cast<const float4*>(x + (size_t)row * EDIM);

        // xx = np.sum(x*x,1): numpy pairwise 8-acc (all lanes redundantly)
        float xxv;
        {
            float4 A = xr4[0], B = xr4[1];
            float r0 = A.x*A.x, r1 = A.y*A.y, r2 = A.z*A.z, r3 = A.w*A.w;
            float r4 = B.x*B.x, r5 = B.y*B.y, r6 = B.z*B.z, r7 = B.w*B.w;
            #pragma unroll
            for (int q = 2; q < 32; q += 2) {
                float4 C = xr4[q], D = xr4[q + 1];
                r0 += C.x*C.x; r1 += C.y*C.y; r2 += C.z*C.z; r3 += C.w*C.w;
                r4 += D.x*D.x; r5 += D.y*D.y; r6 += D.z*D.z; r7 += D.w*D.w;
            }
            xxv = ((r0 + r1) + (r2 + r3)) + ((r4 + r5) + (r6 + r7));
        }

        float dbest = 3.4e38f; int bk = 0;
        #pragma unroll 1
        for (int c = 0; c < 16; c += 2) {           // lane codes ascend: c*64+lane
            int k1 = c * 64 + lane, k2 = k1 + 64;
            const float4* w1 = W4 + (size_t)k1 * 32;
            const float4* w2 = W4 + (size_t)k2 * 32;
            float d1 = 0.f, d2 = 0.f;
            #pragma unroll
            for (int j4 = 0; j4 < 32; ++j4) {       // sequential fmaf chains (sgemm)
                float4 a = xr4[j4];
                float4 u = w1[j4], v = w2[j4];
                d1 = fmaf(a.x, u.x, d1); d1 = fmaf(a.y, u.y, d1);
                d1 = fmaf(a.z, u.z, d1); d1 = fmaf(a.w, u.w, d1);
                d2 = fmaf(a.x, v.x, d2); d2 = fmaf(a.y, v.y, d2);
                d2 = fmaf(a.z, v.z, d2); d2 = fmaf(a.w, v.w, d2);
            }
            float t1 = xxv + swsq_ws[k1];           // fl(xx+wk2)
            float da = t1 - (d1 + d1);              // fl(t1 - fl(2dot))
            if (da < dbest) { dbest = da; bk = k1; }
            float t2 = xxv + swsq_ws[k2];
            float db = t2 - (d2 + d2);
            if (db < dbest) { dbest = db; bk = k2; }
        }
        // cross-lane argmin, first-index on exact ties
        #pragma unroll
        for (int mk = 1; mk < 64; mk <<= 1) {
            float od = __shfl_xor(dbest, mk);
            int   ok = __shfl_xor(bk, mk);
            if (od < dbest || (od == dbest && ok < bk)) { dbest = od; bk = ok; }
        }
        if (lane == 0) idxout[row] = (float)bk;
        zq[(size_t)row * EDIM + lane]      = W[(size_t)bk * EDIM + lane];
        zq[(size_t)row * EDIM + lane + 64] = W[(size_t)bk * EDIM + lane + 64];
    }
}

// ---------------- fallback: round-4 kernel (known-correct, 1507 us) ----------------
__global__ __launch_bounds__(64, 2) void vq_v4(
    const float* __restrict__ x, const float* __restrict__ W,
    float* __restrict__ zq, float* __restrict__ idxout)
{
#pragma clang fp contract(off)
    __shared__ float swsq[NE];
    __shared__ int   sbest[64];
    const int tid = threadIdx.x;
    const long long row0 = (long long)blockIdx.x * 64;
    const long long row  = row0 + tid;
    const float4* x4 = reinterpret_cast<const float4*>(x);
    const float4* W4 = reinterpret_cast<const float4*>(W);
    float4 xr[32];
    #pragma unroll
    for (int i = 0; i < 32; ++i) xr[i] = x4[row * 32 + i];
    #pragma unroll
    for (int i = 0; i < 32; ++i)
        asm volatile("" : "+v"(xr[i].x), "+v"(xr[i].y), "+v"(xr[i].z), "+v"(xr[i].w));
    for (int k = tid; k < NE; k += 64) {
        const float4* wr = W4 + (size_t)k * 32;
        float4 A = wr[0], B = wr[1];
        float r0 = A.x*A.x, r1 = A.y*A.y, r2 = A.z*A.z, r3 = A.w*A.w;
        float r4 = B.x*B.x, r5 = B.y*B.y, r6 = B.z*B.z, r7 = B.w*B.w;
        #pragma unroll
        for (int i = 2; i < 32; i += 2) {
            float4 C = wr[i], D = wr[i + 1];
            r0 += C.x*C.x; r1 += C.y*C.y; r2 += C.z*C.z; r3 += C.w*C.w;
            r4 += D.x*D.x; r5 += D.y*D.y; r6 += D.z*D.z; r7 += D.w*D.w;
        }
        swsq[k] = ((r0 + r1) + (r2 + r3)) + ((r4 + r5) + (r6 + r7));
    }
    float xxv;
    {
        float r0 = xr[0].x*xr[0].x, r1 = xr[0].y*xr[0].y;
        float r2 = xr[0].z*xr[0].z, r3 = xr[0].w*xr[0].w;
        float r4 = xr[1].x*xr[1].x, r5 = xr[1].y*xr[1].y;
        float r6 = xr[1].z*xr[1].z, r7 = xr[1].w*xr[1].w;
        #pragma unroll
        for (int i = 2; i < 32; i += 2) {
            r0 += xr[i].x*xr[i].x;         r1 += xr[i].y*xr[i].y;
            r2 += xr[i].z*xr[i].z;         r3 += xr[i].w*xr[i].w;
            r4 += xr[i+1].x*xr[i+1].x;     r5 += xr[i+1].y*xr[i+1].y;
            r6 += xr[i+1].z*xr[i+1].z;     r7 += xr[i+1].w*xr[i+1].w;
        }
        xxv = ((r0 + r1) + (r2 + r3)) + ((r4 + r5) + (r6 + r7));
    }
    __syncthreads();
    float dbest = 3.4e38f; int bestk = 0;
    #pragma unroll 1
    for (int k0 = 0; k0 < NE; k0 += 8) {
        float acc[8];
        #pragma unroll
        for (int c = 0; c < 8; ++c) acc[c] = 0.f;
        #pragma unroll
        for (int j4 = 0; j4 < 32; ++j4) {
            const float4 a = xr[j4];
            #pragma unroll
            for (int c = 0; c < 8; ++c) {
                float4 w = W4[(size_t)(k0 + c) * 32 + j4];
                acc[c] = fmaf(a.x, w.x, acc[c]); acc[c] = fmaf(a.y, w.y, acc[c]);
                acc[c] = fmaf(a.z, w.z, acc[c]); acc[c] = fmaf(a.w, w.w, acc[c]);
            }
        }
        #pragma unroll
        for (int c = 0; c < 8; ++c) {
            float t1 = xxv + swsq[k0 + c];
            float d  = t1 - (acc[c] + acc[c]);
            if (d < dbest) { dbest = d; bestk = k0 + c; }
        }
    }
    sbest[tid] = bestk;
    idxout[row] = (float)bestk;
    __syncthreads();
    float4* zq4 = reinterpret_cast<float4*>(zq);
    for (int i = tid; i < 64 * 32; i += 64) {
        int r = i >> 5, c4 = i & 31;
        zq4[row0 * 32 + i] = W4[(size_t)sbest[r] * 32 + c4];
    }
}

extern "C" void kernel_launch(void* const* d_in, const int* in_sizes, int n_in,
                              void* d_out, int out_size, void* d_ws, size_t ws_size,
                              hipStream_t stream) {
    (void)n_in; (void)out_size;
    const float* x = (const float*)d_in[0];
    const float* W = (const float*)d_in[1];
    const int Nrows = in_sizes[0] / EDIM;            // 262144

    float* zqp    = (float*)d_out;
    float* idxout = zqp + (size_t)Nrows * EDIM;      // indices stored as float values

    const size_t need = 16 + (size_t)NE * EDIM * 2 * 2 + NE * 4 + (size_t)Nrows * 4;
    if (ws_size < need) {   // no workspace -> proven fp32 path
        vq_v4<<<dim3(Nrows / 64), dim3(64), 0, stream>>>(x, W, zqp, idxout);
        return;
    }

    char* p = (char*)d_ws;
    int*            rcnt  = (int*)p;                       // 16 B
    unsigned short* whi   = (unsigned short*)(p + 16);     // 256 KB
    unsigned short* wlo   = whi + NE * EDIM;               // 256 KB
    float*          swsqw = (float*)(wlo + NE * EDIM);     // 4 KB
    int*            rlist = (int*)(swsqw + NE);            // Nrows ints

    vq_prep<<<dim3(128), dim3(256), 0, stream>>>(W, whi, wlo, swsqw, rcnt);
    vq_mfma<<<dim3(Nrows / 64), dim3(256), 0, stream>>>(x, whi, wlo, W, swsqw,
                                                        zqp, idxout, rcnt, rlist);
    vq_rescue<<<dim3(2048), dim3(64), 0, stream>>>(x, W, swsqw, zqp, idxout,
                                                   rcnt, rlist, Nrows);
}

// Round 9
// 792.663 us; speedup vs baseline: 8.6840x; 1.6337x over previous
//
#include <hip/hip_runtime.h>

#define EDIM 128
#define NE   1024
#define TAU  7e-5f   // grid 3.05e-5 + split err ~1e-5; r8-validated (absmax 0.0 on first pass)

typedef short v8s __attribute__((ext_vector_type(8)));
typedef float v4f __attribute__((ext_vector_type(4)));

__device__ inline unsigned bf16_rne(float f) {
    unsigned u = __float_as_uint(f);
    return (u + 0x7fffu + ((u >> 16) & 1u)) >> 16;
}
__device__ inline float bf16_tof(unsigned h) { return __uint_as_float(h << 16); }

// ---- prep: W -> bf16 hi/lo, W -> Wt (transposed), numpy-exact swsq ----
__global__ void vq_prep(const float* __restrict__ W,
                        unsigned short* __restrict__ whi,
                        unsigned short* __restrict__ wlo,
                        float* __restrict__ Wt,
                        float* __restrict__ swsq_ws)
{
#pragma clang fp contract(off)
    const int t = blockIdx.x * 256 + threadIdx.x;     // 32768 threads
    for (int i = t; i < NE * EDIM; i += 32768) {
        float v = W[i];
        unsigned h = bf16_rne(v);
        whi[i] = (unsigned short)h;
        wlo[i] = (unsigned short)bf16_rne(v - bf16_tof(h));
        Wt[((i & (EDIM - 1)) << 10) | (i >> 7)] = v;   // Wt[j*1024 + k] = W[k*128+j]
    }
    if (t < NE) {   // numpy pairwise 8-acc pattern (validated rounds 2-8)
        const float4* wr = reinterpret_cast<const float4*>(W) + (size_t)t * 32;
        float4 A = wr[0], B = wr[1];
        float r0 = A.x*A.x, r1 = A.y*A.y, r2 = A.z*A.z, r3 = A.w*A.w;
        float r4 = B.x*B.x, r5 = B.y*B.y, r6 = B.z*B.z, r7 = B.w*B.w;
        #pragma unroll
        for (int i = 2; i < 32; i += 2) {
            float4 C = wr[i], D = wr[i + 1];
            r0 += C.x*C.x; r1 += C.y*C.y; r2 += C.z*C.z; r3 += C.w*C.w;
            r4 += D.x*D.x; r5 += D.y*D.y; r6 += D.z*D.z; r7 += D.w*D.w;
        }
        swsq_ws[t] = ((r0 + r1) + (r2 + r3)) + ((r4 + r5) + (r6 + r7));
    }
}

// ---- stage 1: MFMA approx scores; reg-staged dbuf (NO global_load_lds,
//      NO atomics); per-row flag byte; swizzled LDS write+read ----
__global__ __launch_bounds__(256, 3) void vq_mfma3(
    const float* __restrict__ x,
    const unsigned short* __restrict__ whi, const unsigned short* __restrict__ wlo,
    const float* __restrict__ W, const float* __restrict__ swsq_ws,
    float* __restrict__ zq, float* __restrict__ idxout,
    unsigned char* __restrict__ rflag)
{
    __shared__ unsigned short wt[2][2][16 * EDIM];   // 16 KB: [buf][hi/lo][code][k]
    __shared__ float sswsq[NE];                      // 4 KB
    __shared__ int   sbest[128];

    const int tid = threadIdx.x;
    const int wid = tid >> 6;
    const int l   = tid & 63;
    const int m   = l & 15;          // B-code / C-col
    const int g   = l >> 4;          // k-group; C rows g*4+r
    const int kb  = g * 8;

    const long long row0 = (long long)blockIdx.x * 128;
    const float4* x4 = reinterpret_cast<const float4*>(x);
    const float4* W4 = reinterpret_cast<const float4*>(W);

    // write-side swizzle: thread tid stages shorts [tid*8, tid*8+8) of the tile
    // (code = tid>>4, k = (tid&15)*8) to LDS[code*128 + (k ^ ((code&7)<<3))]
    const int scode = tid >> 4;
    const int skk   = (tid & 15) * 8;
    const int dst   = scode * EDIM + (skk ^ ((scode & 7) << 3));
    // read-side swizzle (same involution), r8-validated
    const int swz = (m & 7) << 3;

    reinterpret_cast<float4*>(sswsq)[tid] = reinterpret_cast<const float4*>(swsq_ws)[tid];

    // prologue: tile 0 regs -> LDS buf 0
    {
        v8s h0 = *reinterpret_cast<const v8s*>(whi + tid * 8);
        v8s l0 = *reinterpret_cast<const v8s*>(wlo + tid * 8);
        *reinterpret_cast<v8s*>(&wt[0][0][dst]) = h0;
        *reinterpret_cast<v8s*>(&wt[0][1][dst]) = l0;
    }

    // A-fragments for 2 row-subtiles: rows row0+wid*32+m and +16
    const long long rA0 = row0 + wid * 32 + m;
    const long long rA1 = rA0 + 16;
    v8s a0h[4], a0l[4], a1h[4], a1l[4];
    #pragma unroll
    for (int ks = 0; ks < 4; ++ks) {
        float4 p0 = x4[rA0 * 32 + ks * 8 + g * 2];
        float4 p1 = x4[rA0 * 32 + ks * 8 + g * 2 + 1];
        float4 q0 = x4[rA1 * 32 + ks * 8 + g * 2];
        float4 q1 = x4[rA1 * 32 + ks * 8 + g * 2 + 1];
        float vp[8] = {p0.x,p0.y,p0.z,p0.w,p1.x,p1.y,p1.z,p1.w};
        float vq[8] = {q0.x,q0.y,q0.z,q0.w,q1.x,q1.y,q1.z,q1.w};
        #pragma unroll
        for (int e = 0; e < 8; ++e) {
            unsigned h0 = bf16_rne(vp[e]);
            a0h[ks][e] = (short)h0;
            a0l[ks][e] = (short)bf16_rne(vp[e] - bf16_tof(h0));
            unsigned h1 = bf16_rne(vq[e]);
            a1h[ks][e] = (short)h1;
            a1l[ks][e] = (short)bf16_rne(vq[e] - bf16_tof(h1));
        }
    }
    __syncthreads();   // buf0 + sswsq visible

    float best[8], sec[8]; int bk[8];
    #pragma unroll
    for (int r = 0; r < 8; ++r) { best[r] = 3.4e38f; sec[r] = 3.4e38f; bk[r] = 0; }

    #pragma unroll 1
    for (int t = 0; t < 64; ++t) {
        const int buf = t & 1;

        // prefetch next tile into registers (plain loads; compiler overlaps)
        v8s hn, ln;
        if (t + 1 < 64) {
            hn = *reinterpret_cast<const v8s*>(whi + (t + 1) * 2048 + tid * 8);
            ln = *reinterpret_cast<const v8s*>(wlo + (t + 1) * 2048 + tid * 8);
        }

        v4f acc0 = {0.f,0.f,0.f,0.f}, acc1 = {0.f,0.f,0.f,0.f};
        #pragma unroll
        for (int ks = 0; ks < 4; ++ks) {
            v8s bh = *(const v8s*)&wt[buf][0][(m * EDIM + ks * 32 + kb) ^ swz];
            v8s bl = *(const v8s*)&wt[buf][1][(m * EDIM + ks * 32 + kb) ^ swz];
            acc0 = __builtin_amdgcn_mfma_f32_16x16x32_bf16(a0h[ks], bh, acc0, 0, 0, 0);
            acc0 = __builtin_amdgcn_mfma_f32_16x16x32_bf16(a0l[ks], bh, acc0, 0, 0, 0);
            acc0 = __builtin_amdgcn_mfma_f32_16x16x32_bf16(a0h[ks], bl, acc0, 0, 0, 0);
            acc1 = __builtin_amdgcn_mfma_f32_16x16x32_bf16(a1h[ks], bh, acc1, 0, 0, 0);
            acc1 = __builtin_amdgcn_mfma_f32_16x16x32_bf16(a1l[ks], bh, acc1, 0, 0, 0);
            acc1 = __builtin_amdgcn_mfma_f32_16x16x32_bf16(a1h[ks], bl, acc1, 0, 0, 0);
        }

        const int k = t * 16 + m;
        const float wk2 = sswsq[k];
        #pragma unroll
        for (int r = 0; r < 4; ++r) {
            float s0 = fmaf(-2.f, acc0[r], wk2);
            bool lt0 = s0 < best[r];
            sec[r]  = lt0 ? best[r] : fminf(sec[r], s0);
            bk[r]   = lt0 ? k : bk[r];
            best[r] = lt0 ? s0 : best[r];
            float s1 = fmaf(-2.f, acc1[r], wk2);
            bool lt1 = s1 < best[4 + r];
            sec[4+r]  = lt1 ? best[4+r] : fminf(sec[4+r], s1);
            bk[4+r]   = lt1 ? k : bk[4+r];
            best[4+r] = lt1 ? s1 : best[4+r];
        }

        // write next tile to the other buffer AFTER this tile's reads.
        // buf^1's previous readers drained at the barrier ending iter t-1.
        if (t + 1 < 64) {
            *reinterpret_cast<v8s*>(&wt[buf ^ 1][0][dst]) = hn;
            *reinterpret_cast<v8s*>(&wt[buf ^ 1][1][dst]) = ln;
        }
        __syncthreads();
    }

    // cross-lane top-2 merge over the 16 code-lanes (xor 1,2,4,8 keeps g)
    #pragma unroll
    for (int r = 0; r < 8; ++r) {
        #pragma unroll
        for (int mk = 1; mk < 16; mk <<= 1) {
            float ob = __shfl_xor(best[r], mk);
            int   ok = __shfl_xor(bk[r],   mk);
            float os = __shfl_xor(sec[r],  mk);
            bool take = (ob < best[r]) || (ob == best[r] && ok < bk[r]);
            float loser = take ? best[r] : ob;
            sec[r]  = fminf(fminf(sec[r], os), loser);
            best[r] = take ? ob : best[r];
            bk[r]   = take ? ok : bk[r];
        }
    }

    if (m == 0) {
        #pragma unroll
        for (int r = 0; r < 8; ++r) {
            int rowL = wid * 32 + (r >> 2) * 16 + g * 4 + (r & 3);
            sbest[rowL] = bk[r];
            idxout[row0 + rowL] = (float)bk[r];
            rflag[row0 + rowL] = (unsigned char)((sec[r] - best[r] <= TAU) ? 1 : 0);
        }
    }
    __syncthreads();

    float4* zq4 = reinterpret_cast<float4*>(zq);
    for (int i = tid; i < 128 * 32; i += 256) {
        int r = i >> 5, c4 = i & 31;
        zq4[row0 * 32 + i] = W4[(size_t)sbest[r] * 32 + c4];
    }
}

// ---- stage 2: ballot-driven numpy-bit-exact rescan of flagged rows ----
__global__ __launch_bounds__(256, 4) void vq_rescue3(
    const float* __restrict__ x, const float* __restrict__ Wt,
    const float* __restrict__ W, const float* __restrict__ swsq_ws,
    float* __restrict__ zq, float* __restrict__ idxout,
    const unsigned char* __restrict__ rflag)
{
#pragma clang fp contract(off)
    const int lane = threadIdx.x & 63;
    const int wave = blockIdx.x * 4 + (threadIdx.x >> 6);   // 4096 waves total
    const long long base = (long long)wave * 64;

    const float4* Wt4 = reinterpret_cast<const float4*>(Wt);
    const float4* W4  = reinterpret_cast<const float4*>(W);
    float4* zq4 = reinterpret_cast<float4*>(zq);

    unsigned long long bal = __ballot(rflag[base + lane] != 0);
    while (bal) {
        const int bit = __ffsll((long long)bal) - 1;
        bal &= bal - 1;
        const long long row = base + bit;
        const float4* xr4 = reinterpret_cast<const float4*>(x + row * EDIM);

        // xx: numpy pairwise 8-acc (broadcast loads, all lanes)
        float xxv;
        {
            float4 A = xr4[0], B = xr4[1];
            float r0 = A.x*A.x, r1 = A.y*A.y, r2 = A.z*A.z, r3 = A.w*A.w;
            float r4 = B.x*B.x, r5 = B.y*B.y, r6 = B.z*B.z, r7 = B.w*B.w;
            #pragma unroll
            for (int q = 2; q < 32; q += 2) {
                float4 C = xr4[q], D = xr4[q + 1];
                r0 += C.x*C.x; r1 += C.y*C.y; r2 += C.z*C.z; r3 += C.w*C.w;
                r4 += D.x*D.x; r5 += D.y*D.y; r6 += D.z*D.z; r7 += D.w*D.w;
            }
            xxv = ((r0 + r1) + (r2 + r3)) + ((r4 + r5) + (r6 + r7));
        }

        // 16 sequential-j fmaf chains/lane: codes k = c*256 + lane*4 + e
        float acc[4][4];
        #pragma unroll
        for (int c = 0; c < 4; ++c)
            #pragma unroll
            for (int e = 0; e < 4; ++e) acc[c][e] = 0.f;

        const float* xr = x + row * EDIM;
        #pragma unroll 4
        for (int j = 0; j < EDIM; ++j) {
            float a = xr[j];                                  // wave-uniform
            #pragma unroll
            for (int c = 0; c < 4; ++c) {
                float4 w = Wt4[(size_t)j * 256 + c * 64 + lane];   // coalesced
                acc[c][0] = fmaf(a, w.x, acc[c][0]);
                acc[c][1] = fmaf(a, w.y, acc[c][1]);
                acc[c][2] = fmaf(a, w.z, acc[c][2]);
                acc[c][3] = fmaf(a, w.w, acc[c][3]);
            }
        }

        float dbest = 3.4e38f; int bkk = 0;
        #pragma unroll
        for (int c = 0; c < 4; ++c) {
            #pragma unroll
            for (int e = 0; e < 4; ++e) {
                int k = c * 256 + lane * 4 + e;               // ascending per lane
                float t1 = xxv + swsq_ws[k];                  // fl(xx+wk2)
                float d  = t1 - (acc[c][e] + acc[c][e]);      // fl(t1 - fl(2dot))
                if (d < dbest) { dbest = d; bkk = k; }
            }
        }
        #pragma unroll
        for (int mk = 1; mk < 64; mk <<= 1) {                 // first-index ties
            float od = __shfl_xor(dbest, mk);
            int   ok = __shfl_xor(bkk, mk);
            if (od < dbest || (od == dbest && ok < bkk)) { dbest = od; bkk = ok; }
        }
        if (lane == 0) idxout[row] = (float)bkk;
        if (lane < 32) zq4[row * 32 + lane] = W4[(size_t)bkk * 32 + lane];
    }
}

// ---- fallback: round-4 kernel (known-correct) ----
__global__ __launch_bounds__(64, 2) void vq_v4(
    const float* __restrict__ x, const float* __restrict__ W,
    float* __restrict__ zq, float* __restrict__ idxout)
{
#pragma clang fp contract(off)
    __shared__ float swsq[NE];
    __shared__ int   sbest[64];
    const int tid = threadIdx.x;
    const long long row0 = (long long)blockIdx.x * 64;
    const long long row  = row0 + tid;
    const float4* x4 = reinterpret_cast<const float4*>(x);
    const float4* W4 = reinterpret_cast<const float4*>(W);
    float4 xr[32];
    #pragma unroll
    for (int i = 0; i < 32; ++i) xr[i] = x4[row * 32 + i];
    #pragma unroll
    for (int i = 0; i < 32; ++i)
        asm volatile("" : "+v"(xr[i].x), "+v"(xr[i].y), "+v"(xr[i].z), "+v"(xr[i].w));
    for (int k = tid; k < NE; k += 64) {
        const float4* wr = W4 + (size_t)k * 32;
        float4 A = wr[0], B = wr[1];
        float r0 = A.x*A.x, r1 = A.y*A.y, r2 = A.z*A.z, r3 = A.w*A.w;
        float r4 = B.x*B.x, r5 = B.y*B.y, r6 = B.z*B.z, r7 = B.w*B.w;
        #pragma unroll
        for (int i = 2; i < 32; i += 2) {
            float4 C = wr[i], D = wr[i + 1];
            r0 += C.x*C.x; r1 += C.y*C.y; r2 += C.z*C.z; r3 += C.w*C.w;
            r4 += D.x*D.x; r5 += D.y*D.y; r6 += D.z*D.z; r7 += D.w*D.w;
        }
        swsq[k] = ((r0 + r1) + (r2 + r3)) + ((r4 + r5) + (r6 + r7));
    }
    float xxv;
    {
        float r0 = xr[0].x*xr[0].x, r1 = xr[0].y*xr[0].y;
        float r2 = xr[0].z*xr[0].z, r3 = xr[0].w*xr[0].w;
        float r4 = xr[1].x*xr[1].x, r5 = xr[1].y*xr[1].y;
        float r6 = xr[1].z*xr[1].z, r7 = xr[1].w*xr[1].w;
        #pragma unroll
        for (int i = 2; i < 32; i += 2) {
            r0 += xr[i].x*xr[i].x;     r1 += xr[i].y*xr[i].y;
            r2 += xr[i].z*xr[i].z;     r3 += xr[i].w*xr[i].w;
            r4 += xr[i+1].x*xr[i+1].x; r5 += xr[i+1].y*xr[i+1].y;
            r6 += xr[i+1].z*xr[i+1].z; r7 += xr[i+1].w*xr[i+1].w;
        }
        xxv = ((r0 + r1) + (r2 + r3)) + ((r4 + r5) + (r6 + r7));
    }
    __syncthreads();
    float dbest = 3.4e38f; int bestk = 0;
    #pragma unroll 1
    for (int k0 = 0; k0 < NE; k0 += 8) {
        float acc[8];
        #pragma unroll
        for (int c = 0; c < 8; ++c) acc[c] = 0.f;
        #pragma unroll
        for (int j4 = 0; j4 < 32; ++j4) {
            const float4 a = xr[j4];
            #pragma unroll
            for (int c = 0; c < 8; ++c) {
                float4 w = W4[(size_t)(k0 + c) * 32 + j4];
                acc[c] = fmaf(a.x, w.x, acc[c]); acc[c] = fmaf(a.y, w.y, acc[c]);
                acc[c] = fmaf(a.z, w.z, acc[c]); acc[c] = fmaf(a.w, w.w, acc[c]);
            }
        }
        #pragma unroll
        for (int c = 0; c < 8; ++c) {
            float t1 = xxv + swsq[k0 + c];
            float d  = t1 - (acc[c] + acc[c]);
            if (d < dbest) { dbest = d; bestk = k0 + c; }
        }
    }
    sbest[tid] = bestk;
    idxout[row] = (float)bestk;
    __syncthreads();
    float4* zq4 = reinterpret_cast<float4*>(zq);
    for (int i = tid; i < 64 * 32; i += 64) {
        int r = i >> 5, c4 = i & 31;
        zq4[row0 * 32 + i] = W4[(size_t)sbest[r] * 32 + c4];
    }
}

extern "C" void kernel_launch(void* const* d_in, const int* in_sizes, int n_in,
                              void* d_out, int out_size, void* d_ws, size_t ws_size,
                              hipStream_t stream) {
    (void)n_in; (void)out_size;
    const float* x = (const float*)d_in[0];
    const float* W = (const float*)d_in[1];
    const int Nrows = in_sizes[0] / EDIM;            // 262144

    float* zqp    = (float*)d_out;
    float* idxout = zqp + (size_t)Nrows * EDIM;      // indices stored as float values

    // ws: whi(256K) | wlo(256K) | swsq(4K) | Wt(512K) | rflag(Nrows bytes)
    const size_t need = 2 * (size_t)NE * EDIM * 2 + NE * 4
                      + (size_t)NE * EDIM * 4 + (size_t)Nrows;
    if (ws_size < need) {
        vq_v4<<<dim3(Nrows / 64), dim3(64), 0, stream>>>(x, W, zqp, idxout);
        return;
    }

    char* p = (char*)d_ws;
    unsigned short* whi   = (unsigned short*)p;
    unsigned short* wlo   = whi + NE * EDIM;
    float*          swsqw = (float*)(wlo + NE * EDIM);
    float*          Wt    = swsqw + NE;
    unsigned char*  rflag = (unsigned char*)(Wt + NE * EDIM);

    vq_prep<<<dim3(128), dim3(256), 0, stream>>>(W, whi, wlo, Wt, swsqw);
    vq_mfma3<<<dim3(Nrows / 128), dim3(256), 0, stream>>>(x, whi, wlo, W, swsqw,
                                                          zqp, idxout, rflag);
    vq_rescue3<<<dim3(Nrows / 256), dim3(256), 0, stream>>>(x, Wt, W, swsqw,
                                                            zqp, idxout, rflag);
}

// Round 10
// 495.752 us; speedup vs baseline: 13.8850x; 1.5989x over previous
//
#include <hip/hip_runtime.h>

#define EDIM 128
#define NE   1024
#define TAU  7e-5f   // grid 3.05e-5 + split err ~4e-6 -> 1.8x margin (r8/r9 absmax 0)

typedef short v8s __attribute__((ext_vector_type(8)));
typedef float v4f __attribute__((ext_vector_type(4)));

__device__ inline unsigned bf16_rne(float f) {
    unsigned u = __float_as_uint(f);
    return (u + 0x7fffu + ((u >> 16) & 1u)) >> 16;
}
__device__ inline float bf16_tof(unsigned h) { return __uint_as_float(h << 16); }

// ---- prep: W -> bf16 hi/lo, W -> Wt (transposed), numpy-exact swsq ----
__global__ void vq_prep(const float* __restrict__ W,
                        unsigned short* __restrict__ whi,
                        unsigned short* __restrict__ wlo,
                        float* __restrict__ Wt,
                        float* __restrict__ swsq_ws)
{
#pragma clang fp contract(off)
    const int t = blockIdx.x * 256 + threadIdx.x;     // 32768 threads
    for (int i = t; i < NE * EDIM; i += 32768) {
        float v = W[i];
        unsigned h = bf16_rne(v);
        whi[i] = (unsigned short)h;
        wlo[i] = (unsigned short)bf16_rne(v - bf16_tof(h));
        Wt[((i & (EDIM - 1)) << 10) | (i >> 7)] = v;   // Wt[j*1024 + k]
    }
    if (t < NE) {   // numpy pairwise 8-acc pattern (validated rounds 2-9)
        const float4* wr = reinterpret_cast<const float4*>(W) + (size_t)t * 32;
        float4 A = wr[0], B = wr[1];
        float r0 = A.x*A.x, r1 = A.y*A.y, r2 = A.z*A.z, r3 = A.w*A.w;
        float r4 = B.x*B.x, r5 = B.y*B.y, r6 = B.z*B.z, r7 = B.w*B.w;
        #pragma unroll
        for (int i = 2; i < 32; i += 2) {
            float4 C = wr[i], D = wr[i + 1];
            r0 += C.x*C.x; r1 += C.y*C.y; r2 += C.z*C.z; r3 += C.w*C.w;
            r4 += D.x*D.x; r5 += D.y*D.y; r6 += D.z*D.z; r7 += D.w*D.w;
        }
        swsq_ws[t] = ((r0 + r1) + (r2 + r3)) + ((r4 + r5) + (r6 + r7));
    }
}

union SMem {
    struct { unsigned short wt[2][2][2048]; float sswsq[NE]; } p1;   // 20 KB
    struct { float4 scan[2048]; int sbest[128]; } p2;                // 32.5 KB
};

// ---- stage 1: MFMA approx scores + per-row LDS-scan classification ----
// rflag: 0 = stage-1 winner final, 1 = 2-candidate arbitration, 2 = full rescan
__global__ __launch_bounds__(256, 3) void vq_mfma4(
    const float* __restrict__ x,
    const unsigned short* __restrict__ whi, const unsigned short* __restrict__ wlo,
    const float* __restrict__ W, const float* __restrict__ swsq_ws,
    float* __restrict__ zq, float* __restrict__ idxout,
    unsigned char* __restrict__ rflag, int* __restrict__ k2arr)
{
    __shared__ SMem sm;

    const int tid = threadIdx.x;
    const int wid = tid >> 6;
    const int l   = tid & 63;
    const int m   = l & 15;          // B-code / C-col
    const int g   = l >> 4;          // k-group; C rows g*4+r
    const int kb  = g * 8;

    const long long row0 = (long long)blockIdx.x * 128;
    const float4* x4 = reinterpret_cast<const float4*>(x);
    const float4* W4 = reinterpret_cast<const float4*>(W);

    // write/read LDS swizzle (r8/r9-validated involution)
    const int scode = tid >> 4;
    const int skk   = (tid & 15) * 8;
    const int dst   = scode * EDIM + (skk ^ ((scode & 7) << 3));
    const int swz   = (m & 7) << 3;

    reinterpret_cast<float4*>(sm.p1.sswsq)[tid] =
        reinterpret_cast<const float4*>(swsq_ws)[tid];

    {   // prologue: tile 0 -> LDS buf 0 (reg-staged, swizzled write)
        v8s h0 = *reinterpret_cast<const v8s*>(whi + tid * 8);
        v8s l0 = *reinterpret_cast<const v8s*>(wlo + tid * 8);
        *reinterpret_cast<v8s*>(&sm.p1.wt[0][0][dst]) = h0;
        *reinterpret_cast<v8s*>(&sm.p1.wt[0][1][dst]) = l0;
    }

    // A-fragments for 2 row-subtiles: rows row0+wid*32+m and +16
    const long long rA0 = row0 + wid * 32 + m;
    const long long rA1 = rA0 + 16;
    v8s a0h[4], a0l[4], a1h[4], a1l[4];
    #pragma unroll
    for (int ks = 0; ks < 4; ++ks) {
        float4 p0 = x4[rA0 * 32 + ks * 8 + g * 2];
        float4 p1 = x4[rA0 * 32 + ks * 8 + g * 2 + 1];
        float4 q0 = x4[rA1 * 32 + ks * 8 + g * 2];
        float4 q1 = x4[rA1 * 32 + ks * 8 + g * 2 + 1];
        float vp[8] = {p0.x,p0.y,p0.z,p0.w,p1.x,p1.y,p1.z,p1.w};
        float vq[8] = {q0.x,q0.y,q0.z,q0.w,q1.x,q1.y,q1.z,q1.w};
        #pragma unroll
        for (int e = 0; e < 8; ++e) {
            unsigned h0 = bf16_rne(vp[e]);
            a0h[ks][e] = (short)h0;
            a0l[ks][e] = (short)bf16_rne(vp[e] - bf16_tof(h0));
            unsigned h1 = bf16_rne(vq[e]);
            a1h[ks][e] = (short)h1;
            a1l[ks][e] = (short)bf16_rne(vq[e] - bf16_tof(h1));
        }
    }
    __syncthreads();

    float best[8], sec[8]; int bk[8];
    #pragma unroll
    for (int r = 0; r < 8; ++r) { best[r] = 3.4e38f; sec[r] = 3.4e38f; bk[r] = 0; }

    #pragma unroll 1
    for (int t = 0; t < 64; ++t) {
        const int buf = t & 1;
        v8s hn, ln;
        if (t + 1 < 64) {
            hn = *reinterpret_cast<const v8s*>(whi + (t + 1) * 2048 + tid * 8);
            ln = *reinterpret_cast<const v8s*>(wlo + (t + 1) * 2048 + tid * 8);
        }

        v4f acc0 = {0.f,0.f,0.f,0.f}, acc1 = {0.f,0.f,0.f,0.f};
        #pragma unroll
        for (int ks = 0; ks < 4; ++ks) {
            v8s bh = *(const v8s*)&sm.p1.wt[buf][0][(m * EDIM + ks * 32 + kb) ^ swz];
            v8s bl = *(const v8s*)&sm.p1.wt[buf][1][(m * EDIM + ks * 32 + kb) ^ swz];
            acc0 = __builtin_amdgcn_mfma_f32_16x16x32_bf16(a0h[ks], bh, acc0, 0, 0, 0);
            acc0 = __builtin_amdgcn_mfma_f32_16x16x32_bf16(a0l[ks], bh, acc0, 0, 0, 0);
            acc0 = __builtin_amdgcn_mfma_f32_16x16x32_bf16(a0h[ks], bl, acc0, 0, 0, 0);
            acc1 = __builtin_amdgcn_mfma_f32_16x16x32_bf16(a1h[ks], bh, acc1, 0, 0, 0);
            acc1 = __builtin_amdgcn_mfma_f32_16x16x32_bf16(a1l[ks], bh, acc1, 0, 0, 0);
            acc1 = __builtin_amdgcn_mfma_f32_16x16x32_bf16(a1h[ks], bl, acc1, 0, 0, 0);
        }

        const int k = t * 16 + m;
        const float wk2 = sm.p1.sswsq[k];
        #pragma unroll
        for (int r = 0; r < 4; ++r) {
            float s0 = fmaf(-2.f, acc0[r], wk2);
            bool lt0 = s0 < best[r];
            sec[r]  = lt0 ? best[r] : fminf(sec[r], s0);
            bk[r]   = lt0 ? k : bk[r];
            best[r] = lt0 ? s0 : best[r];
            float s1 = fmaf(-2.f, acc1[r], wk2);
            bool lt1 = s1 < best[4 + r];
            sec[4+r]  = lt1 ? best[4+r] : fminf(sec[4+r], s1);
            bk[4+r]   = lt1 ? k : bk[4+r];
            best[4+r] = lt1 ? s1 : best[4+r];
        }

        if (t + 1 < 64) {
            *reinterpret_cast<v8s*>(&sm.p1.wt[buf ^ 1][0][dst]) = hn;
            *reinterpret_cast<v8s*>(&sm.p1.wt[buf ^ 1][1][dst]) = ln;
        }
        __syncthreads();
    }

    // ---- phase 2: dump per-lane top-2 to LDS, serial per-row scan ----
    #pragma unroll
    for (int r = 0; r < 8; ++r) {
        int rowL = wid * 32 + ((r >> 2) << 4) + (g << 2) + (r & 3);
        float4 e; e.x = best[r]; e.y = sec[r]; e.z = __int_as_float(bk[r]); e.w = 0.f;
        sm.p2.scan[rowL * 16 + m] = e;
    }
    __syncthreads();

    if (tid < 128) {
        // pass 1: global best, lexicographic (value, k)
        float b1 = 3.4e38f; int k1 = 0x7fffffff;
        #pragma unroll 1
        for (int mm = 0; mm < 16; ++mm) {
            float4 e = sm.p2.scan[tid * 16 + mm];
            int kk = __float_as_int(e.z);
            if (e.x < b1 || (e.x == b1 && kk < k1)) { b1 = e.x; k1 = kk; }
        }
        // pass 2: candidate census + global second (among lane-bests, k != k1)
        const float th = b1 + TAU;
        int nb = 0; bool asec = false;
        float b2 = 3.4e38f; int k2 = 0x7fffffff;
        #pragma unroll 1
        for (int mm = 0; mm < 16; ++mm) {
            float4 e = sm.p2.scan[tid * 16 + mm];
            int kk = __float_as_int(e.z);
            nb  += (e.x <= th) ? 1 : 0;
            asec = asec || (e.y <= th);     // a lane may hide a 3rd candidate
            if (kk != k1 && (e.x < b2 || (e.x == b2 && kk < k2))) { b2 = e.x; k2 = kk; }
        }
        unsigned char fl = 0;
        if (asec || nb > 2) fl = 2;         // full exact rescan
        else if (nb == 2)   fl = 1;         // 2-candidate arbitration (k1 vs k2)
        sm.p2.sbest[tid] = k1;
        idxout[row0 + tid] = (float)k1;
        rflag[row0 + tid]  = fl;
        k2arr[row0 + tid]  = (fl == 1) ? k2 : 0;
    }
    __syncthreads();

    float4* zq4 = reinterpret_cast<float4*>(zq);
    for (int i = tid; i < 128 * 32; i += 256) {
        int r = i >> 5, c4 = i & 31;
        zq4[row0 * 32 + i] = W4[(size_t)sm.p2.sbest[r] * 32 + c4];
    }
}

// ---- stage 2a: 2-candidate numpy-exact arbitration (thread per row) ----
__global__ __launch_bounds__(256, 8) void vq_pair(
    const float* __restrict__ x, const float* __restrict__ W,
    const float* __restrict__ swsq_ws,
    float* __restrict__ zq, float* __restrict__ idxout,
    const unsigned char* __restrict__ rflag, const int* __restrict__ k2arr)
{
#pragma clang fp contract(off)
    const int lane = threadIdx.x & 63;
    const long long base = ((long long)blockIdx.x * 4 + (threadIdx.x >> 6)) * 64;
    const long long row = base + lane;

    int newk = -1;
    if (rflag[row] == 1) {
        const int k1 = (int)idxout[row];
        const int k2 = k2arr[row];
        const float4* xr4 = reinterpret_cast<const float4*>(x + row * EDIM);
        // xx: numpy pairwise 8-acc
        float4 A = xr4[0], B = xr4[1];
        float r0 = A.x*A.x, r1 = A.y*A.y, r2 = A.z*A.z, r3 = A.w*A.w;
        float r4 = B.x*B.x, r5 = B.y*B.y, r6 = B.z*B.z, r7 = B.w*B.w;
        #pragma unroll
        for (int q = 2; q < 32; q += 2) {
            float4 C = xr4[q], D = xr4[q + 1];
            r0 += C.x*C.x; r1 += C.y*C.y; r2 += C.z*C.z; r3 += C.w*C.w;
            r4 += D.x*D.x; r5 += D.y*D.y; r6 += D.z*D.z; r7 += D.w*D.w;
        }
        float xxv = ((r0 + r1) + (r2 + r3)) + ((r4 + r5) + (r6 + r7));
        // sequential-j fmaf chains for both candidates (sgemm order)
        const float* xr = x + row * EDIM;
        const float* w1 = W + (size_t)k1 * EDIM;
        const float* w2 = W + (size_t)k2 * EDIM;
        float dot1 = 0.f, dot2 = 0.f;
        #pragma unroll 4
        for (int j = 0; j < EDIM; ++j) {
            float a = xr[j];
            dot1 = fmaf(a, w1[j], dot1);
            dot2 = fmaf(a, w2[j], dot2);
        }
        float d1 = (xxv + swsq_ws[k1]) - (dot1 + dot1);
        float d2 = (xxv + swsq_ws[k2]) - (dot2 + dot2);
        int kw = (d2 < d1 || (d2 == d1 && k2 < k1)) ? k2 : k1;   // first-index
        if (kw != k1) { idxout[row] = (float)kw; newk = kw; }
    }
    // cooperative coalesced zq rewrite for changed rows
    unsigned long long bal = __ballot(newk >= 0);
    const float4* W4 = reinterpret_cast<const float4*>(W);
    float4* zq4 = reinterpret_cast<float4*>(zq);
    while (bal) {
        int bit = __ffsll((long long)bal) - 1;
        bal &= bal - 1;
        long long rrow = base + bit;
        int kk = __shfl(newk, bit);
        if (lane < 32) zq4[rrow * 32 + lane] = W4[(size_t)kk * 32 + lane];
    }
}

// ---- stage 2b: full numpy-exact rescan (rflag==2; expected rare) ----
__global__ __launch_bounds__(256, 4) void vq_full(
    const float* __restrict__ x, const float* __restrict__ Wt,
    const float* __restrict__ W, const float* __restrict__ swsq_ws,
    float* __restrict__ zq, float* __restrict__ idxout,
    const unsigned char* __restrict__ rflag)
{
#pragma clang fp contract(off)
    const int lane = threadIdx.x & 63;
    const long long base = ((long long)blockIdx.x * 4 + (threadIdx.x >> 6)) * 64;
    const float4* Wt4 = reinterpret_cast<const float4*>(Wt);
    const float4* W4  = reinterpret_cast<const float4*>(W);
    float4* zq4 = reinterpret_cast<float4*>(zq);

    unsigned long long bal = __ballot(rflag[base + lane] == 2);
    while (bal) {
        const int bit = __ffsll((long long)bal) - 1;
        bal &= bal - 1;
        const long long row = base + bit;
        const float4* xr4 = reinterpret_cast<const float4*>(x + row * EDIM);
        float xxv;
        {
            float4 A = xr4[0], B = xr4[1];
            float r0 = A.x*A.x, r1 = A.y*A.y, r2 = A.z*A.z, r3 = A.w*A.w;
            float r4 = B.x*B.x, r5 = B.y*B.y, r6 = B.z*B.z, r7 = B.w*B.w;
            #pragma unroll
            for (int q = 2; q < 32; q += 2) {
                float4 C = xr4[q], D = xr4[q + 1];
                r0 += C.x*C.x; r1 += C.y*C.y; r2 += C.z*C.z; r3 += C.w*C.w;
                r4 += D.x*D.x; r5 += D.y*D.y; r6 += D.z*D.z; r7 += D.w*D.w;
            }
            xxv = ((r0 + r1) + (r2 + r3)) + ((r4 + r5) + (r6 + r7));
        }
        float acc[4][4];
        #pragma unroll
        for (int c = 0; c < 4; ++c)
            #pragma unroll
            for (int e = 0; e < 4; ++e) acc[c][e] = 0.f;
        const float* xr = x + row * EDIM;
        #pragma unroll 4
        for (int j = 0; j < EDIM; ++j) {
            float a = xr[j];
            #pragma unroll
            for (int c = 0; c < 4; ++c) {
                float4 w = Wt4[(size_t)j * 256 + c * 64 + lane];
                acc[c][0] = fmaf(a, w.x, acc[c][0]);
                acc[c][1] = fmaf(a, w.y, acc[c][1]);
                acc[c][2] = fmaf(a, w.z, acc[c][2]);
                acc[c][3] = fmaf(a, w.w, acc[c][3]);
            }
        }
        float dbest = 3.4e38f; int bkk = 0;
        #pragma unroll
        for (int c = 0; c < 4; ++c)
            #pragma unroll
            for (int e = 0; e < 4; ++e) {
                int k = c * 256 + lane * 4 + e;
                float t1 = xxv + swsq_ws[k];
                float d  = t1 - (acc[c][e] + acc[c][e]);
                if (d < dbest) { dbest = d; bkk = k; }
            }
        #pragma unroll
        for (int mk = 1; mk < 64; mk <<= 1) {
            float od = __shfl_xor(dbest, mk);
            int   ok = __shfl_xor(bkk, mk);
            if (od < dbest || (od == dbest && ok < bkk)) { dbest = od; bkk = ok; }
        }
        if (lane == 0) idxout[row] = (float)bkk;
        if (lane < 32) zq4[row * 32 + lane] = W4[(size_t)bkk * 32 + lane];
    }
}

// ---- fallback: round-4 kernel (known-correct) ----
__global__ __launch_bounds__(64, 2) void vq_v4(
    const float* __restrict__ x, const float* __restrict__ W,
    float* __restrict__ zq, float* __restrict__ idxout)
{
#pragma clang fp contract(off)
    __shared__ float swsq[NE];
    __shared__ int   sbest[64];
    const int tid = threadIdx.x;
    const long long row0 = (long long)blockIdx.x * 64;
    const long long row  = row0 + tid;
    const float4* x4 = reinterpret_cast<const float4*>(x);
    const float4* W4 = reinterpret_cast<const float4*>(W);
    float4 xr[32];
    #pragma unroll
    for (int i = 0; i < 32; ++i) xr[i] = x4[row * 32 + i];
    #pragma unroll
    for (int i = 0; i < 32; ++i)
        asm volatile("" : "+v"(xr[i].x), "+v"(xr[i].y), "+v"(xr[i].z), "+v"(xr[i].w));
    for (int k = tid; k < NE; k += 64) {
        const float4* wr = W4 + (size_t)k * 32;
        float4 A = wr[0], B = wr[1];
        float r0 = A.x*A.x, r1 = A.y*A.y, r2 = A.z*A.z, r3 = A.w*A.w;
        float r4 = B.x*B.x, r5 = B.y*B.y, r6 = B.z*B.z, r7 = B.w*B.w;
        #pragma unroll
        for (int i = 2; i < 32; i += 2) {
            float4 C = wr[i], D = wr[i + 1];
            r0 += C.x*C.x; r1 += C.y*C.y; r2 += C.z*C.z; r3 += C.w*C.w;
            r4 += D.x*D.x; r5 += D.y*D.y; r6 += D.z*D.z; r7 += D.w*D.w;
        }
        swsq[k] = ((r0 + r1) + (r2 + r3)) + ((r4 + r5) + (r6 + r7));
    }
    float xxv;
    {
        float r0 = xr[0].x*xr[0].x, r1 = xr[0].y*xr[0].y;
        float r2 = xr[0].z*xr[0].z, r3 = xr[0].w*xr[0].w;
        float r4 = xr[1].x*xr[1].x, r5 = xr[1].y*xr[1].y;
        float r6 = xr[1].z*xr[1].z, r7 = xr[1].w*xr[1].w;
        #pragma unroll
        for (int i = 2; i < 32; i += 2) {
            r0 += xr[i].x*xr[i].x;     r1 += xr[i].y*xr[i].y;
            r2 += xr[i].z*xr[i].z;     r3 += xr[i].w*xr[i].w;
            r4 += xr[i+1].x*xr[i+1].x; r5 += xr[i+1].y*xr[i+1].y;
            r6 += xr[i+1].z*xr[i+1].z; r7 += xr[i+1].w*xr[i+1].w;
        }
        xxv = ((r0 + r1) + (r2 + r3)) + ((r4 + r5) + (r6 + r7));
    }
    __syncthreads();
    float dbest = 3.4e38f; int bestk = 0;
    #pragma unroll 1
    for (int k0 = 0; k0 < NE; k0 += 8) {
        float acc[8];
        #pragma unroll
        for (int c = 0; c < 8; ++c) acc[c] = 0.f;
        #pragma unroll
        for (int j4 = 0; j4 < 32; ++j4) {
            const float4 a = xr[j4];
            #pragma unroll
            for (int c = 0; c < 8; ++c) {
                float4 w = W4[(size_t)(k0 + c) * 32 + j4];
                acc[c] = fmaf(a.x, w.x, acc[c]); acc[c] = fmaf(a.y, w.y, acc[c]);
                acc[c] = fmaf(a.z, w.z, acc[c]); acc[c] = fmaf(a.w, w.w, acc[c]);
            }
        }
        #pragma unroll
        for (int c = 0; c < 8; ++c) {
            float t1 = xxv + swsq[k0 + c];
            float d  = t1 - (acc[c] + acc[c]);
            if (d < dbest) { dbest = d; bestk = k0 + c; }
        }
    }
    sbest[tid] = bestk;
    idxout[row] = (float)bestk;
    __syncthreads();
    float4* zq4 = reinterpret_cast<float4*>(zq);
    for (int i = tid; i < 64 * 32; i += 64) {
        int r = i >> 5, c4 = i & 31;
        zq4[row0 * 32 + i] = W4[(size_t)sbest[r] * 32 + c4];
    }
}

extern "C" void kernel_launch(void* const* d_in, const int* in_sizes, int n_in,
                              void* d_out, int out_size, void* d_ws, size_t ws_size,
                              hipStream_t stream) {
    (void)n_in; (void)out_size;
    const float* x = (const float*)d_in[0];
    const float* W = (const float*)d_in[1];
    const int Nrows = in_sizes[0] / EDIM;            // 262144

    float* zqp    = (float*)d_out;
    float* idxout = zqp + (size_t)Nrows * EDIM;      // indices stored as float values

    // ws: whi(256K)|wlo(256K)|swsq(4K)|Wt(512K)|k2arr(Nrows*4)|rflag(Nrows)
    const size_t need = 2 * (size_t)NE * EDIM * 2 + NE * 4
                      + (size_t)NE * EDIM * 4 + (size_t)Nrows * 5;
    if (ws_size < need) {
        vq_v4<<<dim3(Nrows / 64), dim3(64), 0, stream>>>(x, W, zqp, idxout);
        return;
    }

    char* p = (char*)d_ws;
    unsigned short* whi   = (unsigned short*)p;
    unsigned short* wlo   = whi + NE * EDIM;
    float*          swsqw = (float*)(wlo + NE * EDIM);
    float*          Wt    = swsqw + NE;
    int*            k2arr = (int*)(Wt + NE * EDIM);
    unsigned char*  rflag = (unsigned char*)(k2arr + Nrows);

    vq_prep<<<dim3(128), dim3(256), 0, stream>>>(W, whi, wlo, Wt, swsqw);
    vq_mfma4<<<dim3(Nrows / 128), dim3(256), 0, stream>>>(x, whi, wlo, W, swsqw,
                                                          zqp, idxout, rflag, k2arr);
    vq_pair<<<dim3(Nrows / 256), dim3(256), 0, stream>>>(x, W, swsqw,
                                                         zqp, idxout, rflag, k2arr);
    vq_full<<<dim3(Nrows / 256), dim3(256), 0, stream>>>(x, Wt, W, swsqw,
                                                         zqp, idxout, rflag);
}

// Round 11
// 395.659 us; speedup vs baseline: 17.3976x; 1.2530x over previous
//
#include <hip/hip_runtime.h>

#define EDIM 128
#define NE   1024
#define TAU  7e-5f   // grid 3.05e-5 + approx err margin; r8-r10 validated (absmax 0)
#define CAPP 65536   // pair-list capacity (entries); overflow -> full list

typedef short v8s __attribute__((ext_vector_type(8)));
typedef float v4f __attribute__((ext_vector_type(4)));

__device__ inline unsigned bf16_rne(float f) {
    unsigned u = __float_as_uint(f);
    return (u + 0x7fffu + ((u >> 16) & 1u)) >> 16;
}
__device__ inline float bf16_tof(unsigned h) { return __uint_as_float(h << 16); }

// ---- prep: W -> bf16 hi/lo, W -> Wt (transposed), numpy-exact swsq ----
__global__ void vq_prep(const float* __restrict__ W,
                        unsigned short* __restrict__ whi,
                        unsigned short* __restrict__ wlo,
                        float* __restrict__ Wt,
                        float* __restrict__ swsq_ws)
{
#pragma clang fp contract(off)
    const int t = blockIdx.x * 256 + threadIdx.x;     // 32768 threads
    for (int i = t; i < NE * EDIM; i += 32768) {
        float v = W[i];
        unsigned h = bf16_rne(v);
        whi[i] = (unsigned short)h;
        wlo[i] = (unsigned short)bf16_rne(v - bf16_tof(h));
        Wt[((i & (EDIM - 1)) << 10) | (i >> 7)] = v;   // Wt[j*1024 + k]
    }
    if (t < NE) {   // numpy pairwise 8-acc pattern (validated rounds 2-10)
        const float4* wr = reinterpret_cast<const float4*>(W) + (size_t)t * 32;
        float4 A = wr[0], B = wr[1];
        float r0 = A.x*A.x, r1 = A.y*A.y, r2 = A.z*A.z, r3 = A.w*A.w;
        float r4 = B.x*B.x, r5 = B.y*B.y, r6 = B.z*B.z, r7 = B.w*B.w;
        #pragma unroll
        for (int i = 2; i < 32; i += 2) {
            float4 C = wr[i], D = wr[i + 1];
            r0 += C.x*C.x; r1 += C.y*C.y; r2 += C.z*C.z; r3 += C.w*C.w;
            r4 += D.x*D.x; r5 += D.y*D.y; r6 += D.z*D.z; r7 += D.w*D.w;
        }
        swsq_ws[t] = ((r0 + r1) + (r2 + r3)) + ((r4 + r5) + (r6 + r7));
    }
}

union SMem {
    struct { unsigned short wt[2][2][2048]; float sswsq[NE]; } p1;   // 20 KB
    struct { float4 scan[2048]; int sbest[128]; } p2;                // 32.5 KB
};

// ---- stage 1: MFMA approx scores + census -> compacted worklists ----
__global__ __launch_bounds__(256, 3) void vq_mfma5(
    const float* __restrict__ x,
    const unsigned short* __restrict__ whi, const unsigned short* __restrict__ wlo,
    const float* __restrict__ W, const float* __restrict__ swsq_ws,
    float* __restrict__ zq, float* __restrict__ idxout,
    int* __restrict__ cnt_pair, int* __restrict__ cnt_full,
    int* __restrict__ plist, int* __restrict__ flist)
{
    __shared__ SMem sm;

    const int tid = threadIdx.x;
    const int wid = tid >> 6;
    const int l   = tid & 63;
    const int m   = l & 15;          // B-code / C-col
    const int g   = l >> 4;          // k-group; C rows g*4+r
    const int kb  = g * 8;

    const long long row0 = (long long)blockIdx.x * 128;
    const float4* x4 = reinterpret_cast<const float4*>(x);
    const float4* W4 = reinterpret_cast<const float4*>(W);

    // write/read LDS swizzle (r8-r10-validated involution)
    const int scode = tid >> 4;
    const int skk   = (tid & 15) * 8;
    const int dst   = scode * EDIM + (skk ^ ((scode & 7) << 3));
    const int swz   = (m & 7) << 3;

    reinterpret_cast<float4*>(sm.p1.sswsq)[tid] =
        reinterpret_cast<const float4*>(swsq_ws)[tid];

    {   // prologue: tile 0 -> LDS buf 0 (reg-staged, swizzled write)
        v8s h0 = *reinterpret_cast<const v8s*>(whi + tid * 8);
        v8s l0 = *reinterpret_cast<const v8s*>(wlo + tid * 8);
        *reinterpret_cast<v8s*>(&sm.p1.wt[0][0][dst]) = h0;
        *reinterpret_cast<v8s*>(&sm.p1.wt[0][1][dst]) = l0;
    }

    // A-fragments for 2 row-subtiles: rows row0+wid*32+m and +16
    const long long rA0 = row0 + wid * 32 + m;
    const long long rA1 = rA0 + 16;
    v8s a0h[4], a0l[4], a1h[4], a1l[4];
    #pragma unroll
    for (int ks = 0; ks < 4; ++ks) {
        float4 p0 = x4[rA0 * 32 + ks * 8 + g * 2];
        float4 p1 = x4[rA0 * 32 + ks * 8 + g * 2 + 1];
        float4 q0 = x4[rA1 * 32 + ks * 8 + g * 2];
        float4 q1 = x4[rA1 * 32 + ks * 8 + g * 2 + 1];
        float vp[8] = {p0.x,p0.y,p0.z,p0.w,p1.x,p1.y,p1.z,p1.w};
        float vq[8] = {q0.x,q0.y,q0.z,q0.w,q1.x,q1.y,q1.z,q1.w};
        #pragma unroll
        for (int e = 0; e < 8; ++e) {
            unsigned h0 = bf16_rne(vp[e]);
            a0h[ks][e] = (short)h0;
            a0l[ks][e] = (short)bf16_rne(vp[e] - bf16_tof(h0));
            unsigned h1 = bf16_rne(vq[e]);
            a1h[ks][e] = (short)h1;
            a1l[ks][e] = (short)bf16_rne(vq[e] - bf16_tof(h1));
        }
    }
    __syncthreads();

    float best[8], sec[8]; int bk[8];
    #pragma unroll
    for (int r = 0; r < 8; ++r) { best[r] = 3.4e38f; sec[r] = 3.4e38f; bk[r] = 0; }

    #pragma unroll 1
    for (int t = 0; t < 64; ++t) {
        const int buf = t & 1;
        v8s hn, ln;
        if (t + 1 < 64) {
            hn = *reinterpret_cast<const v8s*>(whi + (t + 1) * 2048 + tid * 8);
            ln = *reinterpret_cast<const v8s*>(wlo + (t + 1) * 2048 + tid * 8);
        }

        v4f acc0 = {0.f,0.f,0.f,0.f}, acc1 = {0.f,0.f,0.f,0.f};
        #pragma unroll
        for (int ks = 0; ks < 4; ++ks) {
            v8s bh = *(const v8s*)&sm.p1.wt[buf][0][(m * EDIM + ks * 32 + kb) ^ swz];
            v8s bl = *(const v8s*)&sm.p1.wt[buf][1][(m * EDIM + ks * 32 + kb) ^ swz];
            acc0 = __builtin_amdgcn_mfma_f32_16x16x32_bf16(a0h[ks], bh, acc0, 0, 0, 0);
            acc0 = __builtin_amdgcn_mfma_f32_16x16x32_bf16(a0l[ks], bh, acc0, 0, 0, 0);
            acc0 = __builtin_amdgcn_mfma_f32_16x16x32_bf16(a0h[ks], bl, acc0, 0, 0, 0);
            acc1 = __builtin_amdgcn_mfma_f32_16x16x32_bf16(a1h[ks], bh, acc1, 0, 0, 0);
            acc1 = __builtin_amdgcn_mfma_f32_16x16x32_bf16(a1l[ks], bh, acc1, 0, 0, 0);
            acc1 = __builtin_amdgcn_mfma_f32_16x16x32_bf16(a1h[ks], bl, acc1, 0, 0, 0);
        }

        const int k = t * 16 + m;
        const float wk2 = sm.p1.sswsq[k];
        #pragma unroll
        for (int r = 0; r < 4; ++r) {
            float s0 = fmaf(-2.f, acc0[r], wk2);
            sec[r]  = fminf(sec[r], fmaxf(s0, best[r]));   // top-2 (med3 idiom)
            bk[r]   = (s0 < best[r]) ? k : bk[r];
            best[r] = fminf(best[r], s0);
            float s1 = fmaf(-2.f, acc1[r], wk2);
            sec[4+r]  = fminf(sec[4+r], fmaxf(s1, best[4+r]));
            bk[4+r]   = (s1 < best[4+r]) ? k : bk[4+r];
            best[4+r] = fminf(best[4+r], s1);
        }

        if (t + 1 < 64) {
            *reinterpret_cast<v8s*>(&sm.p1.wt[buf ^ 1][0][dst]) = hn;
            *reinterpret_cast<v8s*>(&sm.p1.wt[buf ^ 1][1][dst]) = ln;
        }
        __syncthreads();
    }

    // ---- dump per-lane top-2 to LDS, per-row serial scan + census ----
    #pragma unroll
    for (int r = 0; r < 8; ++r) {
        int rowL = wid * 32 + ((r >> 2) << 4) + (g << 2) + (r & 3);
        float4 e; e.x = best[r]; e.y = sec[r]; e.z = __int_as_float(bk[r]); e.w = 0.f;
        sm.p2.scan[rowL * 16 + m] = e;
    }
    __syncthreads();

    if (tid < 128) {
        float b1 = 3.4e38f; int k1 = 0x7fffffff;
        #pragma unroll 1
        for (int mm = 0; mm < 16; ++mm) {
            float4 e = sm.p2.scan[tid * 16 + mm];
            int kk = __float_as_int(e.z);
            if (e.x < b1 || (e.x == b1 && kk < k1)) { b1 = e.x; k1 = kk; }
        }
        const float th = b1 + TAU;
        int nb = 0; bool asec = false;
        float b2 = 3.4e38f; int k2 = 0x7fffffff;
        #pragma unroll 1
        for (int mm = 0; mm < 16; ++mm) {
            float4 e = sm.p2.scan[tid * 16 + mm];
            int kk = __float_as_int(e.z);
            nb  += (e.x <= th) ? 1 : 0;
            asec = asec || (e.y <= th);
            if (kk != k1 && (e.x < b2 || (e.x == b2 && kk < k2))) { b2 = e.x; k2 = kk; }
        }
        sm.p2.sbest[tid] = k1;
        idxout[row0 + tid] = (float)k1;
        const int row = (int)(row0 + tid);
        if (asec || nb > 2) {
            int s2 = atomicAdd(cnt_full, 1);
            flist[s2] = row;                       // cap Nrows: cannot overflow
        } else if (nb == 2) {
            int slot = atomicAdd(cnt_pair, 1);
            if (slot < CAPP) { plist[2 * slot] = row; plist[2 * slot + 1] = k2; }
            else { int s2 = atomicAdd(cnt_full, 1); flist[s2] = row; }
        }
    }
    __syncthreads();

    float4* zq4 = reinterpret_cast<float4*>(zq);
    for (int i = tid; i < 128 * 32; i += 256) {
        int r = i >> 5, c4 = i & 31;
        zq4[row0 * 32 + i] = W4[(size_t)sm.p2.sbest[r] * 32 + c4];
    }
}

// ---- stage 2a: 2-candidate numpy-exact arbitration, thread per listed row ----
__global__ __launch_bounds__(256, 8) void vq_pair5(
    const float* __restrict__ x, const float* __restrict__ W,
    const float* __restrict__ swsq_ws,
    float* __restrict__ zq, float* __restrict__ idxout,
    const int* __restrict__ cnt_pair, const int* __restrict__ plist)
{
#pragma clang fp contract(off)
    int n = *cnt_pair; if (n > CAPP) n = CAPP;
    const int gsz = gridDim.x * 256;
    for (int i = blockIdx.x * 256 + threadIdx.x; i < n; i += gsz) {
        const int row = plist[2 * i];
        const int k2  = plist[2 * i + 1];
        const int k1  = (int)idxout[row];
        const float4* xr4 = reinterpret_cast<const float4*>(x + (size_t)row * EDIM);
        // xx: numpy pairwise 8-acc
        float4 A = xr4[0], B = xr4[1];
        float r0 = A.x*A.x, r1 = A.y*A.y, r2 = A.z*A.z, r3 = A.w*A.w;
        float r4 = B.x*B.x, r5 = B.y*B.y, r6 = B.z*B.z, r7 = B.w*B.w;
        #pragma unroll
        for (int q = 2; q < 32; q += 2) {
            float4 C = xr4[q], D = xr4[q + 1];
            r0 += C.x*C.x; r1 += C.y*C.y; r2 += C.z*C.z; r3 += C.w*C.w;
            r4 += D.x*D.x; r5 += D.y*D.y; r6 += D.z*D.z; r7 += D.w*D.w;
        }
        float xxv = ((r0 + r1) + (r2 + r3)) + ((r4 + r5) + (r6 + r7));
        // sequential-j fmaf chains for both candidates (sgemm order)
        const float* xr = x + (size_t)row * EDIM;
        const float* w1 = W + (size_t)k1 * EDIM;
        const float* w2 = W + (size_t)k2 * EDIM;
        float dot1 = 0.f, dot2 = 0.f;
        #pragma unroll 4
        for (int j = 0; j < EDIM; ++j) {
            float a = xr[j];
            dot1 = fmaf(a, w1[j], dot1);
            dot2 = fmaf(a, w2[j], dot2);
        }
        float d1 = (xxv + swsq_ws[k1]) - (dot1 + dot1);
        float d2 = (xxv + swsq_ws[k2]) - (dot2 + dot2);
        int kw = (d2 < d1 || (d2 == d1 && k2 < k1)) ? k2 : k1;   // first-index
        if (kw != k1) {
            idxout[row] = (float)kw;
            const float4* wr = reinterpret_cast<const float4*>(W) + (size_t)kw * 32;
            float4* zr = reinterpret_cast<float4*>(zq) + (size_t)row * 32;
            #pragma unroll
            for (int q = 0; q < 32; ++q) zr[q] = wr[q];
        }
    }
}

// ---- stage 2b: full numpy-exact rescan, wave per listed row ----
__global__ __launch_bounds__(256, 4) void vq_full5(
    const float* __restrict__ x, const float* __restrict__ Wt,
    const float* __restrict__ W, const float* __restrict__ swsq_ws,
    float* __restrict__ zq, float* __restrict__ idxout,
    const int* __restrict__ cnt_full, const int* __restrict__ flist)
{
#pragma clang fp contract(off)
    const int nf = *cnt_full;
    const int lane = threadIdx.x & 63;
    const int nw = gridDim.x * 4;
    const float4* Wt4 = reinterpret_cast<const float4*>(Wt);
    const float4* W4  = reinterpret_cast<const float4*>(W);
    float4* zq4 = reinterpret_cast<float4*>(zq);

    for (int i = blockIdx.x * 4 + (threadIdx.x >> 6); i < nf; i += nw) {
        const long long row = flist[i];
        const float4* xr4 = reinterpret_cast<const float4*>(x + row * EDIM);
        float xxv;
        {
            float4 A = xr4[0], B = xr4[1];
            float r0 = A.x*A.x, r1 = A.y*A.y, r2 = A.z*A.z, r3 = A.w*A.w;
            float r4 = B.x*B.x, r5 = B.y*B.y, r6 = B.z*B.z, r7 = B.w*B.w;
            #pragma unroll
            for (int q = 2; q < 32; q += 2) {
                float4 C = xr4[q], D = xr4[q + 1];
                r0 += C.x*C.x; r1 += C.y*C.y; r2 += C.z*C.z; r3 += C.w*C.w;
                r4 += D.x*D.x; r5 += D.y*D.y; r6 += D.z*D.z; r7 += D.w*D.w;
            }
            xxv = ((r0 + r1) + (r2 + r3)) + ((r4 + r5) + (r6 + r7));
        }
        float acc[4][4];
        #pragma unroll
        for (int c = 0; c < 4; ++c)
            #pragma unroll
            for (int e = 0; e < 4; ++e) acc[c][e] = 0.f;
        const float* xr = x + row * EDIM;
        #pragma unroll 4
        for (int j = 0; j < EDIM; ++j) {
            float a = xr[j];                                  // wave-uniform
            #pragma unroll
            for (int c = 0; c < 4; ++c) {
                float4 w = Wt4[(size_t)j * 256 + c * 64 + lane];   // coalesced
                acc[c][0] = fmaf(a, w.x, acc[c][0]);
                acc[c][1] = fmaf(a, w.y, acc[c][1]);
                acc[c][2] = fmaf(a, w.z, acc[c][2]);
                acc[c][3] = fmaf(a, w.w, acc[c][3]);
            }
        }
        float dbest = 3.4e38f; int bkk = 0;
        #pragma unroll
        for (int c = 0; c < 4; ++c)
            #pragma unroll
            for (int e = 0; e < 4; ++e) {
                int k = c * 256 + lane * 4 + e;               // ascending per lane
                float t1 = xxv + swsq_ws[k];                  // fl(xx+wk2)
                float d  = t1 - (acc[c][e] + acc[c][e]);      // fl(t1 - fl(2dot))
                if (d < dbest) { dbest = d; bkk = k; }
            }
        #pragma unroll
        for (int mk = 1; mk < 64; mk <<= 1) {                 // first-index ties
            float od = __shfl_xor(dbest, mk);
            int   ok = __shfl_xor(bkk, mk);
            if (od < dbest || (od == dbest && ok < bkk)) { dbest = od; bkk = ok; }
        }
        if (lane == 0) idxout[row] = (float)bkk;
        if (lane < 32) zq4[row * 32 + lane] = W4[(size_t)bkk * 32 + lane];
    }
}

// ---- fallback: round-4 kernel (known-correct) ----
__global__ __launch_bounds__(64, 2) void vq_v4(
    const float* __restrict__ x, const float* __restrict__ W,
    float* __restrict__ zq, float* __restrict__ idxout)
{
#pragma clang fp contract(off)
    __shared__ float swsq[NE];
    __shared__ int   sbest[64];
    const int tid = threadIdx.x;
    const long long row0 = (long long)blockIdx.x * 64;
    const long long row  = row0 + tid;
    const float4* x4 = reinterpret_cast<const float4*>(x);
    const float4* W4 = reinterpret_cast<const float4*>(W);
    float4 xr[32];
    #pragma unroll
    for (int i = 0; i < 32; ++i) xr[i] = x4[row * 32 + i];
    #pragma unroll
    for (int i = 0; i < 32; ++i)
        asm volatile("" : "+v"(xr[i].x), "+v"(xr[i].y), "+v"(xr[i].z), "+v"(xr[i].w));
    for (int k = tid; k < NE; k += 64) {
        const float4* wr = W4 + (size_t)k * 32;
        float4 A = wr[0], B = wr[1];
        float r0 = A.x*A.x, r1 = A.y*A.y, r2 = A.z*A.z, r3 = A.w*A.w;
        float r4 = B.x*B.x, r5 = B.y*B.y, r6 = B.z*B.z, r7 = B.w*B.w;
        #pragma unroll
        for (int i = 2; i < 32; i += 2) {
            float4 C = wr[i], D = wr[i + 1];
            r0 += C.x*C.x; r1 += C.y*C.y; r2 += C.z*C.z; r3 += C.w*C.w;
            r4 += D.x*D.x; r5 += D.y*D.y; r6 += D.z*D.z; r7 += D.w*D.w;
        }
        swsq[k] = ((r0 + r1) + (r2 + r3)) + ((r4 + r5) + (r6 + r7));
    }
    float xxv;
    {
        float r0 = xr[0].x*xr[0].x, r1 = xr[0].y*xr[0].y;
        float r2 = xr[0].z*xr[0].z, r3 = xr[0].w*xr[0].w;
        float r4 = xr[1].x*xr[1].x, r5 = xr[1].y*xr[1].y;
        float r6 = xr[1].z*xr[1].z, r7 = xr[1].w*xr[1].w;
        #pragma unroll
        for (int i = 2; i < 32; i += 2) {
            r0 += xr[i].x*xr[i].x;     r1 += xr[i].y*xr[i].y;
            r2 += xr[i].z*xr[i].z;     r3 += xr[i].w*xr[i].w;
            r4 += xr[i+1].x*xr[i+1].x; r5 += xr[i+1].y*xr[i+1].y;
            r6 += xr[i+1].z*xr[i+1].z; r7 += xr[i+1].w*xr[i+1].w;
        }
        xxv = ((r0 + r1) + (r2 + r3)) + ((r4 + r5) + (r6 + r7));
    }
    __syncthreads();
    float dbest = 3.4e38f; int bestk = 0;
    #pragma unroll 1
    for (int k0 = 0; k0 < NE; k0 += 8) {
        float acc[8];
        #pragma unroll
        for (int c = 0; c < 8; ++c) acc[c] = 0.f;
        #pragma unroll
        for (int j4 = 0; j4 < 32; ++j4) {
            const float4 a = xr[j4];
            #pragma unroll
            for (int c = 0; c < 8; ++c) {
                float4 w = W4[(size_t)(k0 + c) * 32 + j4];
                acc[c] = fmaf(a.x, w.x, acc[c]); acc[c] = fmaf(a.y, w.y, acc[c]);
                acc[c] = fmaf(a.z, w.z, acc[c]); acc[c] = fmaf(a.w, w.w, acc[c]);
            }
        }
        #pragma unroll
        for (int c = 0; c < 8; ++c) {
            float t1 = xxv + swsq[k0 + c];
            float d  = t1 - (acc[c] + acc[c]);
            if (d < dbest) { dbest = d; bestk = k0 + c; }
        }
    }
    sbest[tid] = bestk;
    idxout[row] = (float)bestk;
    __syncthreads();
    float4* zq4 = reinterpret_cast<float4*>(zq);
    for (int i = tid; i < 64 * 32; i += 64) {
        int r = i >> 5, c4 = i & 31;
        zq4[row0 * 32 + i] = W4[(size_t)sbest[r] * 32 + c4];
    }
}

extern "C" void kernel_launch(void* const* d_in, const int* in_sizes, int n_in,
                              void* d_out, int out_size, void* d_ws, size_t ws_size,
                              hipStream_t stream) {
    (void)n_in; (void)out_size;
    const float* x = (const float*)d_in[0];
    const float* W = (const float*)d_in[1];
    const int Nrows = in_sizes[0] / EDIM;            // 262144

    float* zqp    = (float*)d_out;
    float* idxout = zqp + (size_t)Nrows * EDIM;      // indices stored as float values

    // ws: cnts(16)|whi(256K)|wlo(256K)|swsq(4K)|Wt(512K)|plist(512K)|flist(1M)
    const size_t need = 16 + 2 * (size_t)NE * EDIM * 2 + NE * 4
                      + (size_t)NE * EDIM * 4 + (size_t)CAPP * 2 * 4
                      + (size_t)Nrows * 4;
    if (ws_size < need) {
        vq_v4<<<dim3(Nrows / 64), dim3(64), 0, stream>>>(x, W, zqp, idxout);
        return;
    }

    char* p = (char*)d_ws;
    int*            cnt_pair = (int*)p;                    // [0]
    int*            cnt_full = (int*)(p + 4);              // [1]
    unsigned short* whi   = (unsigned short*)(p + 16);
    unsigned short* wlo   = whi + NE * EDIM;
    float*          swsqw = (float*)(wlo + NE * EDIM);
    float*          Wt    = swsqw + NE;
    int*            plist = (int*)(Wt + NE * EDIM);        // CAPP x {row,k2}
    int*            flist = plist + CAPP * 2;              // Nrows rows

    hipMemsetAsync(d_ws, 0, 16, stream);                   // r7-proven reset
    vq_prep<<<dim3(128), dim3(256), 0, stream>>>(W, whi, wlo, Wt, swsqw);
    vq_mfma5<<<dim3(Nrows / 128), dim3(256), 0, stream>>>(x, whi, wlo, W, swsqw,
                                                          zqp, idxout,
                                                          cnt_pair, cnt_full,
                                                          plist, flist);
    vq_pair5<<<dim3(256), dim3(256), 0, stream>>>(x, W, swsqw, zqp, idxout,
                                                  cnt_pair, plist);
    vq_full5<<<dim3(512), dim3(256), 0, stream>>>(x, Wt, W, swsqw, zqp, idxout,
                                                  cnt_full, flist);
}